// Round 3
// baseline (705.636 us; speedup 1.0000x reference)
//
#include <hip/hip_runtime.h>

// Locally-connected conv, MI355X. Round 3.
// Block = (h, 4-w strip, 32-o half); wave wv = position p. 32b x 32o x 288k
// GEMM per position via mfma_f32_32x32x16_bf16, K in 4 chunks of 72 (+8 zero pad).
// R3 vs R2:
//  - W (B-operand) loaded DIRECTLY global->VGPR per lane (k contiguous per
//    (h,w,o) row, immediate offsets), converted to bf16 in-reg. No W LDS stage.
//  - Pl double-buffered, ONE barrier per chunk (one vmcnt drain, full-chunk
//    prefetch distance for both W and x loads).
//  - Pl layout [p][k-unit16B][b][8]: A-frag ds_read_b128 is a contiguous
//    1024-B wave read (conflict-free). LDS = 40 KB -> 4 blocks/CU.
//  - Grid swizzle: 4 blocks sharing an output 64-B line get equal bid%8
//    (same XCD) and adjacent dispatch -> partial stores merge in L2.

#define NP 4
#define KU 10   // 16-B k-units per row: 9 data (72 bf16) + 1 zero pad
#define PLBUF (NP * KU * 256)   // bf16 elems per buffer (20480 B)

typedef __attribute__((ext_vector_type(8))) short short8;
typedef __attribute__((ext_vector_type(4))) int int4v;
typedef __attribute__((ext_vector_type(16))) float f32x16;

__device__ __forceinline__ unsigned f2bf(float f) {
    unsigned u = __builtin_bit_cast(unsigned, f);
    return (u + 0x7FFFu + ((u >> 16) & 1u)) >> 16;   // RNE, finite inputs
}

__device__ __forceinline__ short8 cvt8(float4 a, float4 b) {
    int4v r;
    r.x = (int)(f2bf(a.x) | (f2bf(a.y) << 16));
    r.y = (int)(f2bf(a.z) | (f2bf(a.w) << 16));
    r.z = (int)(f2bf(b.x) | (f2bf(b.y) << 16));
    r.w = (int)(f2bf(b.z) | (f2bf(b.w) << 16));
    return __builtin_bit_cast(short8, r);
}

__device__ __forceinline__ void load_x(const float* __restrict__ xg, int h, int w0,
                                       int tid, int c0, float2* xreg) {
#pragma unroll
    for (int it = 0; it < 12; it++) {
        int task = it * 256 + tid;
        int f2i = task & 3, row = task >> 2;
        int b = row / 24, rem = row - b * 24;
        int c = rem / 3, y3 = rem - c * 3;
        int y = h + y3 - 1;
        int gx0 = w0 - 2 + 2 * f2i;
        if ((unsigned)y < 64u && (unsigned)gx0 < 64u)
            xreg[it] = *(const float2*)(xg + ((b * 32 + c0 + c) * 64 + y) * 64 + gx0);
        else
            xreg[it] = float2{0.f, 0.f};
    }
}

__device__ __forceinline__ void fanout(unsigned short* Plb, int tid, const float2* xreg) {
    // col xc (0..7; global w = w0+xc-2) feeds taps (p,j) with p+j = xc-1.
#pragma unroll
    for (int it = 0; it < 12; it++) {
        int task = it * 256 + tid;
        int f2i = task & 3, row = task >> 2;
        int b = row / 24, rem = row - b * 24;
        int c = rem / 3, y3 = rem - c * 3;
        int kb = c * 9 + y3 * 3;
        unsigned bx0 = f2bf(xreg[it].x), bx1 = f2bf(xreg[it].y);
#pragma unroll
        for (int qq = 0; qq < 2; qq++) {
            int xc = f2i * 2 + qq;
            unsigned short bv = (unsigned short)(qq ? bx1 : bx0);
#pragma unroll
            for (int j = 0; j < 3; j++) {
                int p = xc - 1 - j;
                if ((unsigned)p < 4u) {
                    int k = kb + j;
                    Plb[(p * KU + (k >> 3)) * 256 + b * 8 + (k & 7)] = bv;
                }
            }
        }
    }
}

__global__ __launch_bounds__(256, 4) void lcconv_kernel(
    const float* __restrict__ xg,    // [32][32][64][64]
    const float* __restrict__ wg,    // [64][64][64][32][3][3]
    const float* __restrict__ bg,    // [64][64][64]
    float* __restrict__ outg)        // [32][64][64][64]
{
    __shared__ unsigned short Pl[2 * PLBUF];   // 40960 B

    const int tid = threadIdx.x;
    const int bid = blockIdx.x;
    // swizzle: siblings (same h,oh, ws-group of 4) share bid%8 (XCD), adjacent bids
    const int xr = bid & 7;
    const int q  = bid >> 3;
    const int s  = q & 3;
    const int u  = ((q >> 2) << 3) | xr;   // 0..511
    const int h  = u >> 3;
    const int t  = (u & 7) >> 1;
    const int oh = u & 1;
    const int w0 = (t * 4 + s) * 4;
    const int og = oh * 32;

    const int lane = tid & 63;
    const int wv   = tid >> 6;     // position p
    const int mrow = lane & 31;
    const int g    = lane >> 5;

    // zero the k-pad unit (ku=9) of all rows in both buffers
    {
        int bufp = tid >> 7;
        int rp   = tid & 127;
        int p = rp >> 5, b = rp & 31;
        *(short8*)&Pl[bufp * PLBUF + ((p * KU + 9) * 32 + b) * 8] = (short8)0;
    }

    f32x16 acc;
#pragma unroll
    for (int i = 0; i < 16; i++) acc[i] = 0.f;

    // per-lane W row: (h, w0+wv, og+mrow, :) — 288 floats = 72 float4, contiguous
    const float4* wrow = (const float4*)(wg + (((h * 64 + w0 + wv) * 64) + og + mrow) * 288);

    float4 breg[5][2];
    float2 xreg[12];

    // prologue: chunk-0 loads
    load_x(xg, h, w0, tid, 0, xreg);
#pragma unroll
    for (int ks = 0; ks < 5; ks++) {
        int fo = ks * 4 + g * 2;           // pad lanes (ks=4,g=1) read valid bytes; A-pad zeroes them
        breg[ks][0] = wrow[fo];
        breg[ks][1] = wrow[fo + 1];
    }

#pragma unroll
    for (int cc = 0; cc < 4; cc++) {
        unsigned short* Plb = Pl + (cc & 1) * PLBUF;
        fanout(Plb, tid, xreg);
        __syncthreads();
        if (cc < 3) load_x(xg, h, w0, tid, (cc + 1) * 8, xreg);

        const unsigned short* Arow = Plb + (wv * KU) * 256 + mrow * 8;
#pragma unroll
        for (int ks = 0; ks < 5; ks++) {
            short8 afrag = *(const short8*)(Arow + (ks * 2 + g) * 256);
            short8 bfrag = cvt8(breg[ks][0], breg[ks][1]);
            if (cc < 3) {   // reload right after last use: full-chunk prefetch distance
                int fo = (cc + 1) * 18 + ks * 4 + g * 2;
                fo = fo > 70 ? 70 : fo;            // clamp OOB pad lanes in-bounds
                int fo1 = fo + 1 > 71 ? 71 : fo + 1;
                breg[ks][0] = wrow[fo];
                breg[ks][1] = wrow[fo1];
            }
            acc = __builtin_amdgcn_mfma_f32_32x32x16_bf16(afrag, bfrag, acc, 0, 0, 0);
        }
    }

    // epilogue: C frags -> LDS transpose (buffer 0; last MFMA read buffer 1) -> stores
    float* outl = (float*)Pl;   // [p][b][o] fp32, 16384 B
#pragma unroll
    for (int r = 0; r < 16; r++) {
        int row = (r & 3) + 8 * (r >> 2) + 4 * g;   // b (verified C/D layout)
        outl[(wv * 32 + row) * 32 + mrow] = acc[r];
    }
    __syncthreads();

#pragma unroll
    for (int it = 0; it < 4; it++) {
        int id = it * 256 + tid;
        int b = id >> 5, o = id & 31;
        float4 v;
        v.x = outl[0 * 1024 + b * 32 + o];
        v.y = outl[1 * 1024 + b * 32 + o];
        v.z = outl[2 * 1024 + b * 32 + o];
        v.w = outl[3 * 1024 + b * 32 + o];
        const float4 bb = *(const float4*)(bg + ((og + o) * 64 + h) * 64 + w0);
        v.x += bb.x; v.y += bb.y; v.z += bb.z; v.w += bb.w;
        *(float4*)(outg + ((b * 64 + og + o) * 64 + h) * 64 + w0) = v;
    }
}

extern "C" void kernel_launch(void* const* d_in, const int* in_sizes, int n_in,
                              void* d_out, int out_size, void* d_ws, size_t ws_size,
                              hipStream_t stream) {
    const float* x = (const float*)d_in[0];
    const float* w = (const float*)d_in[1];
    const float* b = (const float*)d_in[2];
    float* out = (float*)d_out;
    lcconv_kernel<<<dim3(2048), dim3(256), 0, stream>>>(x, w, b, out);
}